// Round 16
// baseline (52.295 us; speedup 1.0000x reference)
//
#include <hip/hip_runtime.h>
#include <cfloat>

#define NEG_INF_F (-1e30f)

constexpr int BB = 8, SS = 4096, HH = 1024;
constexpr int TOTAL = BB * SS;   // 32768 rows
constexpr int MAXLEN = 30;
constexpr int TPR = 8;           // threads per row
constexpr int CPT = 4;           // candidates per thread (ceil(30/8))
constexpr int RPW = 64 / TPR;    // 8 rows per wave
constexpr int WPB = 4;           // waves per block (256 threads)
constexpr int RPB = RPW * WPB;   // 32 rows per block
constexpr int S1_GRID = TOTAL / RPB;          // 1024 blocks = 4096 waves
constexpr int WAVES_PER_B = (SS / RPB) * WPB; // 512 waves per batch

// ---------------- Kernel 1: QA-head GEMV + masking (proven ~20.5 us) ---------
// NOTE: plain __launch_bounds__(256) only — a min-waves hint caps VGPRs and
// serializes the 12 in-flight loads (R6/R8: 370 GB/s disaster).
__global__ __launch_bounds__(256) void qa_logits_kernel(
    const float* __restrict__ X,     // (B*S, H)
    const float* __restrict__ mask,  // (B*S)
    const float* __restrict__ W,     // (H, 2) row-major
    const float* __restrict__ bqa,   // (2)
    float* __restrict__ out) {       // [0,TOTAL): start, [TOTAL,2*TOTAL): end
  int row  = (int)((blockIdx.x * (size_t)blockDim.x + threadIdx.x) >> 6);
  int lane = threadIdx.x & 63;
  if (row >= TOTAL) return;
  const float* rp = X + (size_t)row * HH;
  float s0 = 0.f, s1 = 0.f;
#pragma unroll
  for (int k = 0; k < HH / 256; ++k) {
    int h = (k * 64 + lane) * 4;
    const float4 x   = *reinterpret_cast<const float4*>(rp + h);
    const float4 w01 = *reinterpret_cast<const float4*>(W + 2 * h);
    const float4 w23 = *reinterpret_cast<const float4*>(W + 2 * h + 4);
    s0 += x.x * w01.x + x.y * w01.z + x.z * w23.x + x.w * w23.z;
    s1 += x.x * w01.y + x.y * w01.w + x.z * w23.y + x.w * w23.w;
  }
#pragma unroll
  for (int off = 32; off > 0; off >>= 1) {
    s0 += __shfl_down(s0, off);
    s1 += __shfl_down(s1, off);
  }
  if (lane == 0) {
    float m = mask[row];
    float inv = 1.f - m;
    out[row]         = (s0 + bqa[0]) * m + inv * NEG_INF_F;
    out[TOTAL + row] = (s1 + bqa[1]) * m + inv * NEG_INF_F;
  }
}

// ---------- packed u64 key: (sortable-float << 32) | (~idx) ----------
// Higher key = higher value, then lower flat index (jax top_k tie-break).
// Validated end-to-end in rounds 8-15.
__device__ __forceinline__ unsigned long long pack_key(float v, unsigned idx) {
  unsigned u = __float_as_uint(v);
  u = (u & 0x80000000u) ? ~u : (u | 0x80000000u);
  return ((unsigned long long)u << 32) | (unsigned long long)(0xFFFFFFFFu - idx);
}

// Sorted-descending 5-key insert, early exit (keys unique, 0 = sentinel).
__device__ __forceinline__ void k5_insert(unsigned long long k[5], unsigned long long nk) {
  if (nk <= k[4]) return;
  k[4] = nk;
  unsigned long long t;
  if (k[4] > k[3]) { t = k[3]; k[3] = k[4]; k[4] = t; }
  if (k[3] > k[2]) { t = k[2]; k[2] = k[3]; k[3] = t; }
  if (k[2] > k[1]) { t = k[1]; k[1] = k[2]; k[2] = t; }
  if (k[1] > k[0]) { t = k[0]; k[0] = k[1]; k[1] = t; }
}

// Wave-wide top-5 via butterfly sorted-list merge (R2/R3-proven pattern):
// after round r, each lane holds top-5 of its 2^(r+1)-lane group; after 6
// rounds all 64 lanes hold the wave top-5. Dependent-shuffle chain is ~3x
// shorter than 5 serial argmax rounds (the R11-R15 stage-1 bottleneck).
__device__ __forceinline__ void wave_merge5(unsigned long long k[5]) {
#pragma unroll
  for (int off = 1; off < 64; off <<= 1) {
    unsigned long long o0 = __shfl_xor(k[0], off);
    unsigned long long o1 = __shfl_xor(k[1], off);
    unsigned long long o2 = __shfl_xor(k[2], off);
    unsigned long long o3 = __shfl_xor(k[3], off);
    unsigned long long o4 = __shfl_xor(k[4], off);
    k5_insert(k, o0);
    k5_insert(k, o1);
    k5_insert(k, o2);
    k5_insert(k, o3);
    k5_insert(k, o4);
  }
}

// ---------------- Stage 1: high-TLP short-chain banded top-5 ----------------
// 1024 blocks x 256 threads = 4096 waves (4 waves/SIMD -> real TLP).
// 8 threads/row, 4 candidates each; direct L2 loads (R14-proven), no LDS,
// no barriers; butterfly merge; each wave writes its 5 keys.
__global__ __launch_bounds__(256) void topk_stage1(
    const float* __restrict__ logits,      // gemv output (start then end)
    unsigned long long* __restrict__ ws) { // (4096 waves, 5) keys
  const int t = (int)threadIdx.x;
  const int lane = t & 63;
  const int w = t >> 6;
  const int grow0 = blockIdx.x * RPB;       // first global row of block
  const int lr = lane >> 3;                 // row within wave 0..7
  const int sub = lane & 7;                 // candidate slice
  const int grow = grow0 + w * RPW + lr;    // global row
  const int b = grow >> 12;                 // batch
  const int i = grow & (SS - 1);            // row within batch

  const float* st = logits + (size_t)b * SS;
  const float* en = logits + (size_t)(BB + b) * SS;

  unsigned long long k5[5] = {0, 0, 0, 0, 0};
  const float sv = st[i];                   // 8 lanes share -> broadcast fetch

  if (i >= 4) {
    const int c0 = sub * CPT;
    float e[CPT];
#pragma unroll
    for (int c = 0; c < CPT; ++c) {
      int cc = c0 + c;
      int j = i + cc;
      // Unguarded load: max addr = 2*TOTAL-1+31 < out_size (65616).
      float v = en[j];
      e[c] = (cc < MAXLEN && j < SS) ? v : NEG_INF_F;
    }
    unsigned base = (unsigned)(i * SS + i + c0);
#pragma unroll
    for (int c = 0; c < CPT; ++c) k5_insert(k5, pack_key(sv + e[c], base + c));
  } else if (i >= 1 && sub == 0) {          // spans (1,1),(2,2),(3,3)
    k5_insert(k5, pack_key(sv + en[i], (unsigned)(i * SS + i)));
  }

  wave_merge5(k5);

  if (lane == 0) {
    const int wave_id = blockIdx.x * WPB + w;
#pragma unroll
    for (int q = 0; q < 5; ++q) ws[wave_id * 5 + q] = k5[q];
  }
}

// ---------------- Stage 2: per-batch merge of 512 waves * 5 = 2560 keys -----
// 40 keys/lane, coalesced parallel loads, early-exit inserts, butterfly merge.
__global__ __launch_bounds__(64) void topk_stage2(
    const unsigned long long* __restrict__ ws,
    float* __restrict__ out) {
  const int b = blockIdx.x;
  const int lane = (int)threadIdx.x;
  const unsigned long long* src = ws + (size_t)b * WAVES_PER_B * 5;  // 2560

  unsigned long long k5[5] = {0, 0, 0, 0, 0};
#pragma unroll
  for (int q = 0; q < 40; ++q) k5_insert(k5, src[q * 64 + lane]);

  wave_merge5(k5);

  if (lane == 0) {
    float* ts = out + 2 * (size_t)TOTAL;  // top_start region
    float* te = ts + BB * 5;              // top_end region
#pragma unroll
    for (int q = 0; q < 5; ++q) {
      unsigned idx = 0xFFFFFFFFu - (unsigned)(k5[q] & 0xFFFFFFFFull);
      ts[b * 5 + q] = (float)(idx >> 12);       // idx / S  (S=4096)
      te[b * 5 + q] = (float)(idx & (SS - 1));  // idx % S
    }
  }
}

extern "C" void kernel_launch(void* const* d_in, const int* in_sizes, int n_in,
                              void* d_out, int out_size, void* d_ws, size_t ws_size,
                              hipStream_t stream) {
  const float* X    = (const float*)d_in[0];  // (B,S,H)
  const float* mask = (const float*)d_in[1];  // (B,S)
  const float* W    = (const float*)d_in[2];  // (H,2)
  const float* bqa  = (const float*)d_in[3];  // (2)
  float* out = (float*)d_out;
  unsigned long long* ws = (unsigned long long*)d_ws;  // 4096*5 u64 = 160 KB

  qa_logits_kernel<<<TOTAL / 4, 256, 0, stream>>>(X, mask, W, bqa, out);
  topk_stage1<<<S1_GRID, 256, 0, stream>>>(out, ws);
  topk_stage2<<<BB, 64, 0, stream>>>(ws, out);
}

// Round 17
// 33.983 us; speedup vs baseline: 1.5389x; 1.5389x over previous
//
#include <hip/hip_runtime.h>
#include <cfloat>

#define NEG_INF_F (-1e30f)

constexpr int BB = 8, SS = 4096, HH = 1024;
constexpr int TOTAL = BB * SS;   // 32768 rows
constexpr int MAXLEN = 30;
constexpr int RPW = 16;          // rows per wave (4 threads/row, 8 cand/thread)
constexpr int WPB = 4;           // waves per block
constexpr int RPB = RPW * WPB;   // 64 rows per block
constexpr int BLK_PER_B = SS / RPB;          // 64
constexpr int S1_GRID = BB * BLK_PER_B;      // 512 blocks = 2048 waves
constexpr int WAVES_PER_B = BLK_PER_B * WPB; // 256 waves per batch

// ---------------- Kernel 1: QA-head GEMV + masking (proven ~20.5 us) ---------
// NOTE: plain __launch_bounds__(256) only — a min-waves hint caps VGPRs and
// serializes the 12 in-flight loads (R6/R8: 370 GB/s disaster).
__global__ __launch_bounds__(256) void qa_logits_kernel(
    const float* __restrict__ X,     // (B*S, H)
    const float* __restrict__ mask,  // (B*S)
    const float* __restrict__ W,     // (H, 2) row-major
    const float* __restrict__ bqa,   // (2)
    float* __restrict__ out) {       // [0,TOTAL): start, [TOTAL,2*TOTAL): end
  int row  = (int)((blockIdx.x * (size_t)blockDim.x + threadIdx.x) >> 6);
  int lane = threadIdx.x & 63;
  if (row >= TOTAL) return;
  const float* rp = X + (size_t)row * HH;
  float s0 = 0.f, s1 = 0.f;
#pragma unroll
  for (int k = 0; k < HH / 256; ++k) {
    int h = (k * 64 + lane) * 4;
    const float4 x   = *reinterpret_cast<const float4*>(rp + h);
    const float4 w01 = *reinterpret_cast<const float4*>(W + 2 * h);
    const float4 w23 = *reinterpret_cast<const float4*>(W + 2 * h + 4);
    s0 += x.x * w01.x + x.y * w01.z + x.z * w23.x + x.w * w23.z;
    s1 += x.x * w01.y + x.y * w01.w + x.z * w23.y + x.w * w23.w;
  }
#pragma unroll
  for (int off = 32; off > 0; off >>= 1) {
    s0 += __shfl_down(s0, off);
    s1 += __shfl_down(s1, off);
  }
  if (lane == 0) {
    float m = mask[row];
    float inv = 1.f - m;
    out[row]         = (s0 + bqa[0]) * m + inv * NEG_INF_F;
    out[TOTAL + row] = (s1 + bqa[1]) * m + inv * NEG_INF_F;
  }
}

// ---------- packed u64 key: (sortable-float << 32) | (~idx) ----------
// Higher key = higher value, then lower flat index (jax top_k tie-break).
// Validated end-to-end in rounds 8-16.
__device__ __forceinline__ unsigned long long pack_key(float v, unsigned idx) {
  unsigned u = __float_as_uint(v);
  u = (u & 0x80000000u) ? ~u : (u | 0x80000000u);
  return ((unsigned long long)u << 32) | (unsigned long long)(0xFFFFFFFFu - idx);
}

// Sorted-descending 5-key insert, early exit (keys unique, 0 = sentinel).
__device__ __forceinline__ void k5_insert(unsigned long long k[5], unsigned long long nk) {
  if (nk <= k[4]) return;
  k[4] = nk;
  unsigned long long t;
  if (k[4] > k[3]) { t = k[3]; k[3] = k[4]; k[4] = t; }
  if (k[3] > k[2]) { t = k[2]; k[2] = k[3]; k[3] = t; }
  if (k[2] > k[1]) { t = k[1]; k[1] = k[2]; k[2] = t; }
  if (k[1] > k[0]) { t = k[0]; k[0] = k[1]; k[1] = t; }
}

// Wave-wide top-5 via 5 argmax rounds on u64 keys; result same in all lanes.
// Measured best merge (R16's butterfly alternative was +18 us: divergent
// branchy inserts x 6 rounds lose badly to 5 branchless argmax rounds).
__device__ __forceinline__ void wave_top5_u64(unsigned long long k[5],
                                              unsigned long long r[5]) {
#pragma unroll
  for (int q = 0; q < 5; ++q) {
    unsigned long long m = k[0];
    if (k[1] > m) m = k[1];
    if (k[2] > m) m = k[2];
    if (k[3] > m) m = k[3];
    if (k[4] > m) m = k[4];
#pragma unroll
    for (int off = 1; off < 64; off <<= 1) {
      unsigned long long o = __shfl_xor(m, off);
      if (o > m) m = o;
    }
    r[q] = m;
#pragma unroll
    for (int p = 0; p < 5; ++p)
      if (k[p] == m) k[p] = 0ull;  // keys unique; invalidate winner
  }
}

// ---------------- Stage 1: barrier-free direct-load banded top-5 (R14) ------
// 512 blocks x 256 threads = 2048 independent waves; wave = 16 rows x 4 subs.
// Logits are cache-resident (freshly written, 256 KB) -> direct global loads,
// all 8 issued in parallel, NO LDS, NO __syncthreads, ONE wave_top5 on the
// critical path. Each wave writes its own 5 keys.
__global__ __launch_bounds__(256) void topk_stage1(
    const float* __restrict__ logits,      // gemv output (start then end)
    unsigned long long* __restrict__ ws) { // (2048 waves, 5) keys
  const int t = (int)threadIdx.x;
  const int lane = t & 63;
  const int w = t >> 6;
  const int b  = blockIdx.x / BLK_PER_B;
  const int rb = blockIdx.x % BLK_PER_B;
  const int lr = lane >> 2;            // row within wave 0..15
  const int sub = lane & 3;            // candidate slice
  const int i = rb * RPB + w * RPW + lr;

  const float* st = logits + (size_t)b * SS;
  const float* en = logits + (size_t)(BB + b) * SS;

  unsigned long long k5[5] = {0, 0, 0, 0, 0};
  const float sv = st[i];              // 4 lanes share -> broadcast fetch

  if (i >= 4) {
    const int c0 = sub * 8;
    float e[8];
#pragma unroll
    for (int c = 0; c < 8; ++c) {
      int cc = c0 + c;
      int j = i + cc;
      // Unguarded load: max addr = logits[2*TOTAL-1 + 30] < out_size (65616).
      // OOB-of-batch values are replaced by NEG_INF via the select below.
      float v = en[j];
      e[c] = (cc < MAXLEN && j < SS) ? v : NEG_INF_F;
    }
    unsigned base = (unsigned)(i * SS + i + c0);
#pragma unroll
    for (int c = 0; c < 8; ++c) k5_insert(k5, pack_key(sv + e[c], base + c));
  } else if (i >= 1 && sub == 0) {     // spans (1,1),(2,2),(3,3)
    k5_insert(k5, pack_key(sv + en[i], (unsigned)(i * SS + i)));
  }

  unsigned long long r5[5];
  wave_top5_u64(k5, r5);

  if (lane == 0) {
    const int wave_id = blockIdx.x * WPB + w;
#pragma unroll
    for (int q = 0; q < 5; ++q) ws[wave_id * 5 + q] = r5[q];
  }
}

// ---------------- Stage 2: per-batch merge of 256 waves * 5 = 1280 keys -----
__global__ __launch_bounds__(64) void topk_stage2(
    const unsigned long long* __restrict__ ws,
    float* __restrict__ out) {
  const int b = blockIdx.x;
  const int lane = (int)threadIdx.x;
  const unsigned long long* src = ws + (size_t)b * WAVES_PER_B * 5;  // 1280

  unsigned long long g[20];
#pragma unroll
  for (int q = 0; q < 20; ++q) g[q] = src[q * 64 + lane];  // coalesced, parallel

  unsigned long long k5[5] = {0, 0, 0, 0, 0};
#pragma unroll
  for (int q = 0; q < 20; ++q) k5_insert(k5, g[q]);

  unsigned long long r5[5];
  wave_top5_u64(k5, r5);

  if (lane == 0) {
    float* ts = out + 2 * (size_t)TOTAL;  // top_start region
    float* te = ts + BB * 5;              // top_end region
#pragma unroll
    for (int q = 0; q < 5; ++q) {
      unsigned idx = 0xFFFFFFFFu - (unsigned)(r5[q] & 0xFFFFFFFFull);
      ts[b * 5 + q] = (float)(idx >> 12);       // idx / S  (S=4096)
      te[b * 5 + q] = (float)(idx & (SS - 1));  // idx % S
    }
  }
}

extern "C" void kernel_launch(void* const* d_in, const int* in_sizes, int n_in,
                              void* d_out, int out_size, void* d_ws, size_t ws_size,
                              hipStream_t stream) {
  const float* X    = (const float*)d_in[0];  // (B,S,H)
  const float* mask = (const float*)d_in[1];  // (B,S)
  const float* W    = (const float*)d_in[2];  // (H,2)
  const float* bqa  = (const float*)d_in[3];  // (2)
  float* out = (float*)d_out;
  unsigned long long* ws = (unsigned long long*)d_ws;  // 2048*5 u64 = 80 KB

  qa_logits_kernel<<<TOTAL / 4, 256, 0, stream>>>(X, mask, W, bqa, out);
  topk_stage1<<<S1_GRID, 256, 0, stream>>>(out, ws);
  topk_stage2<<<BB, 64, 0, stream>>>(ws, out);
}